// Round 6
// baseline (127401.892 us; speedup 1.0000x reference)
//
#include <hip/hip_runtime.h>
#include <hip/hip_bf16.h>

typedef __bf16 bf16x8 __attribute__((ext_vector_type(8)));
typedef __bf16 bf16x4 __attribute__((ext_vector_type(4)));
typedef float floatx4 __attribute__((ext_vector_type(4)));
typedef unsigned long long ull;

#define AGT __HIP_MEMORY_SCOPE_AGENT
#define WGS __HIP_MEMORY_SCOPE_WORKGROUP

// ---- communication primitives ----
// AGT (sc1/L3): proven cross-XCD visibility (r0/r5). Used by SLOW path.
__device__ __forceinline__ ull cload(const ull* p) {
    return __hip_atomic_load(const_cast<ull*>(p), __ATOMIC_RELAXED, AGT);
}
__device__ __forceinline__ unsigned fload(const unsigned* p) {
    return __hip_atomic_load(const_cast<unsigned*>(p), __ATOMIC_RELAXED, AGT);
}
__device__ __forceinline__ void cstore32(unsigned* p, unsigned v) {
    __hip_atomic_store(p, v, __ATOMIC_RELAXED, AGT);
}
// L2-scope coherent read via RMW(+0): atomics execute at the XCD's L2 and
// cannot be served stale from L1 (r4 showed sc0 LOADS do not bypass L1).
__device__ __forceinline__ unsigned l2rmw0(unsigned* p) {
    return __hip_atomic_fetch_add(p, 0u, __ATOMIC_RELAXED, WGS);
}
__device__ __forceinline__ float fsig(float x) { return 1.f / (1.f + __expf(-x)); }
__device__ __forceinline__ float ftanh(float x) { return 1.f - 2.f / (__expf(2.f * x) + 1.f); }

// ---------------- prep kernels ----------------

__global__ __launch_bounds__(256) void prep_x(const float* __restrict__ x,
                                              __hip_bfloat16* __restrict__ Xb) {
    int t = blockIdx.x * 256 + threadIdx.x;
    int row = t >> 4, c8 = (t & 15) * 8;
    union { __hip_bfloat16 h[8]; uint4 u; } pk;
#pragma unroll
    for (int j = 0; j < 8; j++) {
        int col = c8 + j;
        float v = (col < 100) ? x[row * 100 + col] : 0.f;
        pk.h[j] = __float2bfloat16(v);
    }
    *reinterpret_cast<uint4*>(Xb + (size_t)row * 128 + c8) = pk.u;
}

__global__ __launch_bounds__(256) void prep_wcat(const float* __restrict__ Wih, int Kin, int K1,
                                                 const float* __restrict__ Whh,
                                                 __hip_bfloat16* __restrict__ Wcat, int ldW) {
    int k = blockIdx.x * 256 + threadIdx.x;
    int row = blockIdx.y;
    if (k >= ldW) return;
    float v;
    if (k < K1) v = (k < Kin) ? Wih[row * Kin + k] : 0.f;
    else        v = Whh[row * 384 + (k - K1)];
    Wcat[row * ldW + k] = __float2bfloat16(v);
}

__global__ __launch_bounds__(256) void init_zero(__hip_bfloat16* __restrict__ H0b,
                                                 __hip_bfloat16* __restrict__ H1b,
                                                 unsigned* __restrict__ bar) {
    int i = blockIdx.x * 256 + threadIdx.x;
    __hip_bfloat16 z = __float2bfloat16(0.f);
    H0b[i] = z; H1b[i] = z;
    if (i < 4096) bar[i] = 0u;
}

__global__ __launch_bounds__(256) void wtmp_k(const float* __restrict__ W3,
                                              const float* __restrict__ W2,
                                              float* __restrict__ Wtmp) {
    int idx = blockIdx.x * 256 + threadIdx.x;
    int j = idx / 512, i = idx % 512;
    float a[8] = {0,0,0,0,0,0,0,0};
    for (int q = 0; q < 1024; q += 8) {
#pragma unroll
        for (int u = 0; u < 8; u++)
            a[u] += W3[j * 1024 + q + u] * W2[(q + u) * 512 + i];
    }
    Wtmp[idx] = ((a[0]+a[1])+(a[2]+a[3])) + ((a[4]+a[5])+(a[6]+a[7]));
}

__global__ __launch_bounds__(256) void weff_k(const float* __restrict__ Wtmp,
                                              const float* __restrict__ W1,
                                              float* __restrict__ Weff) {
    int idx = blockIdx.x * 256 + threadIdx.x;
    if (idx >= 3840) return;
    int j = idx / 384, i = idx % 384;
    float a[8] = {0,0,0,0,0,0,0,0};
    for (int q = 0; q < 512; q += 8) {
#pragma unroll
        for (int u = 0; u < 8; u++)
            a[u] += Wtmp[j * 512 + q + u] * W1[(q + u) * 384 + i];
    }
    Weff[idx] = ((a[0]+a[1])+(a[2]+a[3])) + ((a[4]+a[5])+(a[6]+a[7]));
}

__global__ __launch_bounds__(256) void beff_k(const float* __restrict__ W3, const float* __restrict__ b2,
                       const float* __restrict__ Wtmp, const float* __restrict__ b1,
                       const float* __restrict__ b3, float* __restrict__ beff) {
    __shared__ float red[256];
    int tid = threadIdx.x;
    for (int j = 0; j < 10; j++) {
        float p = 0.f;
        for (int q = tid; q < 1024; q += 256) p += W3[j * 1024 + q] * b2[q];
        for (int q = tid; q < 512; q += 256)  p += Wtmp[j * 512 + q] * b1[q];
        red[tid] = p;
        __syncthreads();
        for (int s = 128; s > 0; s >>= 1) {
            if (tid < s) red[tid] += red[tid + s];
            __syncthreads();
        }
        if (tid == 0) beff[j] = red[0] + b3[j];
        __syncthreads();
    }
}

// ---------------- persistent pipelined LSTM (512-thread blocks) ----------------
// 192 blocks = 8 groups x 2 layers x 12 gate-blocks; all 24 blocks of a group
// share (bid mod 8) -> one XCD (r4/r5: rendezvous declares FAST on HW).
// Evidence ledger: r5 proved data-tier (L2 vs L3) is OFF the critical path;
// r4 proved sc0 LOADS don't bypass L1 (stale poll). This round attacks the
// sync legs: L2-scope counters (WGS fetch_add publish; RMW(+0) poll — atomics
// execute at L2, immune to L1 staleness), per-wave publish after per-wave
// vmcnt(0) drain (counter target 96*t), end-of-loop barrier removed, and
// L0's Xb fragments prefetched before the poll. SLOW path = proven AGT/L3.

__device__ __forceinline__ bf16x8 lds_frag(const short* As, int r, int k) {
    const short* p = As + r * 388 + k;
    bf16x4 lo = *reinterpret_cast<const bf16x4*>(p);
    bf16x4 hi = *reinterpret_cast<const bf16x4*>(p + 4);
    return __builtin_shufflevector(lo, hi, 0, 1, 2, 3, 4, 5, 6, 7);
}

// stage 32 rows x 384 bf16 (24576B) into LDS (row stride 388 shorts), 512 thr
template<int FAST>
__device__ __forceinline__ void stage512(short* As, const ull* src, int tid) {
    ull v[6];
#pragma unroll
    for (int i = 0; i < 6; i++)
        v[i] = FAST ? src[tid + 512 * i] : cload(src + tid + 512 * i);
#pragma unroll
    for (int i = 0; i < 6; i++) {
        int q = tid + 512 * i;          // 0..3071 (96 ull per row)
        int row = q / 96;
        int c8 = q - row * 96;
        *reinterpret_cast<ull*>(As + row * 388 + c8 * 4) = v[i];
    }
}
// stage two slices, all 12 loads outstanding before scatter
template<int FAST>
__device__ __forceinline__ void stage512x2(short* Asa, const ull* sa,
                                           short* Asb, const ull* sb, int tid) {
    ull va[6], vb[6];
#pragma unroll
    for (int i = 0; i < 6; i++)
        va[i] = FAST ? sa[tid + 512 * i] : cload(sa + tid + 512 * i);
#pragma unroll
    for (int i = 0; i < 6; i++)
        vb[i] = FAST ? sb[tid + 512 * i] : cload(sb + tid + 512 * i);
#pragma unroll
    for (int i = 0; i < 6; i++) {
        int q = tid + 512 * i;
        int row = q / 96;
        int c8 = q - row * 96;
        *reinterpret_cast<ull*>(Asa + row * 388 + c8 * 4) = va[i];
        *reinterpret_cast<ull*>(Asb + row * 388 + c8 * 4) = vb[i];
    }
}

template<int L, int FAST>
__device__ void run_chain(
    const __hip_bfloat16* __restrict__ Xb,
    const __hip_bfloat16* __restrict__ Wcat,
    const float* __restrict__ bih, const float* __restrict__ bhh,
    const __hip_bfloat16* __restrict__ Hin,   // L=1: producer's H0
    __hip_bfloat16* __restrict__ Hown,
    unsigned* ctr_own, unsigned* ctr_prod,
    short* As1, short* As2, float* gbuf,
    int g, int bsub, int tid)
{
    constexpr int NKI = (L ? 12 : 4);
    constexpr int NK  = NKI + 12;
    constexpr int LDW = (L ? 768 : 512);
    int lane = tid & 63, wv = tid >> 6;        // wv 0..7
    int g4 = wv & 3, nt = wv >> 2;             // gate, n-half
    int lane15 = lane & 15, koff = (lane >> 4) * 8;

    // ---- register-resident weight fragments: ONE nt per wave ----
    bf16x8 bw[NK];
    {
        const __hip_bfloat16* Wrow =
            Wcat + (size_t)(g4 * 384 + bsub * 32 + nt * 16 + lane15) * LDW;
#pragma unroll
        for (int kk = 0; kk < NK; kk++)
            bw[kk] = *reinterpret_cast<const bf16x8*>(Wrow + kk * 32 + koff);
    }

    // ---- cell-thread state: m = tid>>4 (0..31), dims d0..d0+1 ----
    int m = tid >> 4, d0 = (tid & 15) * 2;
    int dgl = bsub * 32 + d0;
    float bb[4][2];
#pragma unroll
    for (int j = 0; j < 4; j++)
#pragma unroll
        for (int jj = 0; jj < 2; jj++)
            bb[j][jj] = bih[j * 384 + dgl + jj] + bhh[j * 384 + dgl + jj];
    float cst[2] = {0.f, 0.f};

    const __hip_bfloat16* XbRow = (L == 0) ? (Xb + (size_t)(g * 32 + lane15) * 128 + koff) : nullptr;
    unsigned* hout = reinterpret_cast<unsigned*>(Hown + (size_t)(g * 32 + m) * 384 + dgl);
    const ull* hsrc_own = reinterpret_cast<const ull*>(Hown + (size_t)g * 12288);
    const ull* hsrc_in  = L ? reinterpret_cast<const ull*>(Hin + (size_t)g * 12288) : nullptr;

    int r0 = (lane >> 4) * 4, ccol = lane15;

    // guards: legit waits are <<100 iters. Broken-sync worst case completes the
    // bench (passed, slow, diagnosable) instead of hanging the container.
    constexpr unsigned GUARD = FAST ? (1u << 12) : (1u << 13);

#pragma unroll 1
    for (int t = 0; t < 256; t++) {
        // ---- L0: prefetch Xb fragments (h-independent) under the poll ----
        bf16x8 ax[2][4];
        if (L == 0) {
            const __hip_bfloat16* A1p = XbRow + (size_t)t * 32768;
#pragma unroll
            for (int mt = 0; mt < 2; mt++)
#pragma unroll
                for (int kk = 0; kk < 4; kk++)
                    ax[mt][kk] = *reinterpret_cast<const bf16x8*>(A1p + mt * 2048 + kk * 32);
        }

        // ---- wait: own ctr >= 96t; L1 also producer >= 96(t+1) ----
        if (tid < 64) {
            if (FAST) {
                // L2-resident RMW(+0) poll: lanes 0 (own) and 1 (producer, L1)
                for (unsigned it = 0; ; ++it) {
                    unsigned f = 0xFFFFFFFFu, nv = 0u;
                    if (lane == 0)               { f = l2rmw0(ctr_own);  nv = 96u * (unsigned)t; }
                    else if (L == 1 && lane == 1){ f = l2rmw0(ctr_prod); nv = 96u * (unsigned)(t + 1); }
                    if (__ballot(f >= nv) == ~0ull) break;
                    if (it > GUARD) break;
                }
            } else {
                unsigned need = 96u * (unsigned)t;
                const unsigned* pp = ctr_own;
                if (L == 1 && lane == 1) { pp = ctr_prod; need += 96u; }
                for (unsigned it = 0; ; ++it) {
                    unsigned f = fload(pp);
                    if (__ballot(f >= need) == ~0ull) break;
                    if (it > GUARD) break;
                    __builtin_amdgcn_s_sleep(1);
                }
            }
        }
        __syncthreads();
        asm volatile("" ::: "memory");

        floatx4 acc[2];
        acc[0] = floatx4{0.f, 0.f, 0.f, 0.f};
        acc[1] = floatx4{0.f, 0.f, 0.f, 0.f};

        if (L == 0) {
            stage512<FAST>(As2, hsrc_own + (size_t)t * 12288, tid);
            // input-part MFMAs overlap the stage loads
#pragma unroll
            for (int kk = 0; kk < 4; kk++)
#pragma unroll
                for (int mt = 0; mt < 2; mt++)
                    acc[mt] = __builtin_amdgcn_mfma_f32_16x16x32_bf16(ax[mt][kk], bw[kk], acc[mt], 0, 0, 0);
            __syncthreads();
        } else {
            stage512x2<FAST>(As1, hsrc_in + (size_t)(t + 1) * 12288,
                             As2, hsrc_own + (size_t)t * 12288, tid);
            __syncthreads();
#pragma unroll
            for (int kk = 0; kk < 12; kk++)
#pragma unroll
                for (int mt = 0; mt < 2; mt++) {
                    bf16x8 a = lds_frag(As1, mt * 16 + lane15, kk * 32 + koff);
                    acc[mt] = __builtin_amdgcn_mfma_f32_16x16x32_bf16(a, bw[kk], acc[mt], 0, 0, 0);
                }
        }
#pragma unroll
        for (int kk = 0; kk < 12; kk++)
#pragma unroll
            for (int mt = 0; mt < 2; mt++) {
                bf16x8 a = lds_frag(As2, mt * 16 + lane15, kk * 32 + koff);
                acc[mt] = __builtin_amdgcn_mfma_f32_16x16x32_bf16(a, bw[NKI + kk], acc[mt], 0, 0, 0);
            }
        if (L == 1) __syncthreads();   // gbuf aliases As1 (read by L1 MFMAs)

        // ---- gates to LDS: C layout row=(lane>>4)*4+r, col=lane&15 ----
#pragma unroll
        for (int mt = 0; mt < 2; mt++)
#pragma unroll
            for (int r = 0; r < 4; r++)
                gbuf[g4 * 1056 + (mt * 16 + r0 + r) * 33 + nt * 16 + ccol] = acc[mt][r];
        __syncthreads();

        // ---- cell update (2 dims/thread) + h store ----
        union { unsigned u; __hip_bfloat16 h[2]; } pk;
#pragma unroll
        for (int jj = 0; jj < 2; jj++) {
            float gi = gbuf[0 * 1056 + m * 33 + d0 + jj] + bb[0][jj];
            float gf = gbuf[1 * 1056 + m * 33 + d0 + jj] + bb[1][jj];
            float gg = gbuf[2 * 1056 + m * 33 + d0 + jj] + bb[2][jj];
            float go = gbuf[3 * 1056 + m * 33 + d0 + jj] + bb[3][jj];
            float c = fsig(gf) * cst[jj] + fsig(gi) * ftanh(gg);
            cst[jj] = c;
            pk.h[jj] = __float2bfloat16(fsig(go) * ftanh(c));
        }
        if (FAST) *(hout + (size_t)(t + 1) * 49152) = pk.u;   // L2 write-through
        else      cstore32(hout + (size_t)(t + 1) * 49152, pk.u);

        // ---- per-wave publish: drain own stores, then +1 (no end barrier) ----
        asm volatile("s_waitcnt vmcnt(0)" ::: "memory");
        if (lane == 0) {
            if (FAST) __hip_atomic_fetch_add(ctr_own, 1u, __ATOMIC_RELAXED, WGS); // L2
            else      __hip_atomic_fetch_add(ctr_own, 1u, __ATOMIC_RELAXED, AGT); // L3
        }
        // next-iter safety: bar after the poll orders gbuf/As reuse; each
        // wave's publish is ordered after its own h stores by the vmcnt wait.
    }
}

__global__ __launch_bounds__(512, 2) void lstm_persistent(
    const __hip_bfloat16* __restrict__ Xb,
    const __hip_bfloat16* __restrict__ Wcat0,
    const __hip_bfloat16* __restrict__ Wcat1,
    const float* __restrict__ bih0, const float* __restrict__ bhh0,
    const float* __restrict__ bih1, const float* __restrict__ bhh1,
    __hip_bfloat16* __restrict__ H0, __hip_bfloat16* __restrict__ H1,
    unsigned* __restrict__ bar)
{
    __shared__ __align__(16) char smem[49664];
    short* As1 = (short*)smem;              // L1 staged h0; aliases gbuf
    short* As2 = (short*)(smem + 24832);    // staged own h
    float* gbuf = (float*)smem;             // phase-disjoint with As1
    __shared__ int fast_s;

    int tid = threadIdx.x;
    int bid = blockIdx.x;
    // XCD-affine mapping: all 24 blocks of group g share (bid mod 8) == g.
    int g = bid & 7;
    int l = (bid >> 3) & 1;
    int bsub = bid >> 4;

    // ---- one-time rendezvous: publish XCC id, decide fast/slow per group ----
    // bar[0]=rendezvous ctr, bar[8..199]=xcc table (+1), bar[256..]=chain ctrs
    if (tid < 64) {
        unsigned xcc;
        asm volatile("s_getreg_b32 %0, hwreg(20, 0, 4)" : "=s"(xcc));  // HW_REG_XCC_ID
        if (tid == 0) {
            __hip_atomic_store(&bar[8 + bid], xcc + 1u, __ATOMIC_RELEASE, AGT);
            __hip_atomic_fetch_add(&bar[0], 1u, __ATOMIC_RELEASE, AGT);
        }
        unsigned r;
        unsigned it2 = 0;
        do {
            r = __hip_atomic_load(&bar[0], __ATOMIC_ACQUIRE, AGT);
            if (r < 192u) __builtin_amdgcn_s_sleep(8);
            if (++it2 > (1u << 22)) break;   // hang guard (~1s); forces fallback
        } while (r < 192u);
        int ok = (r >= 192u) ? 1 : 0;        // rendezvous timeout -> slow path
        if (ok && tid < 24) {   // my group's 24 members all on my XCC?
            int ob = g + (tid & 1) * 8 + (tid >> 1) * 16;
            ok = (fload(&bar[8 + ob]) == xcc + 1u);
        }
        int fast = (__ballot(ok) == ~0ull) ? 1 : 0;
        if (tid == 0) {
            // hwreg sanity: 8 group representatives must be pairwise distinct
            unsigned rep[8];
            for (int j = 0; j < 8; j++) rep[j] = fload(&bar[8 + j]);
            for (int a2 = 0; a2 < 8; a2++)
                for (int b2 = a2 + 1; b2 < 8; b2++)
                    if (rep[a2] == rep[b2]) fast = 0;
            fast_s = fast;
        }
    }
    __syncthreads();
    int fast = fast_s;

    // chain ctr lines: one 128B line per group ((g*2+l)*64B) -> no cross-XCD
    // false sharing of L2 lines in FAST mode.
    unsigned* ctrs = bar + 256;
    unsigned* ctr_own = ctrs + (g * 2 + l) * 16;
    unsigned* ctr_prod = ctrs + (g * 2) * 16;  // L0 chain of this group

    if (l == 0) {
        if (fast) run_chain<0, 1>(Xb, Wcat0, bih0, bhh0, nullptr, H0,
                                  ctr_own, nullptr, As1, As2, gbuf, g, bsub, tid);
        else      run_chain<0, 0>(Xb, Wcat0, bih0, bhh0, nullptr, H0,
                                  ctr_own, nullptr, As1, As2, gbuf, g, bsub, tid);
    } else {
        if (fast) run_chain<1, 1>(nullptr, Wcat1, bih1, bhh1, H0, H1,
                                  ctr_own, ctr_prod, As1, As2, gbuf, g, bsub, tid);
        else      run_chain<1, 0>(nullptr, Wcat1, bih1, bhh1, H0, H1,
                                  ctr_own, ctr_prod, As1, As2, gbuf, g, bsub, tid);
    }
}

// ---------------- emissions ----------------
__global__ __launch_bounds__(256) void em_kernel(const __hip_bfloat16* __restrict__ H1,
                                                 const float* __restrict__ Weff,
                                                 const float* __restrict__ beff,
                                                 float* __restrict__ em) {
    __shared__ __hip_bfloat16 At[256 * 68];
    __shared__ float Wt[640];
    __shared__ float bf[10];
    int tid = threadIdx.x;
    int row0 = blockIdx.x * 256;
    if (tid < 10) bf[tid] = beff[tid];
    float acc[10];
#pragma unroll
    for (int j = 0; j < 10; j++) acc[j] = 0.f;

    for (int kt = 0; kt < 384; kt += 64) {
        __syncthreads();
#pragma unroll
        for (int q = 0; q < 16; q++) {
            int flat = q * 256 + tid;
            int r = flat >> 4;
            int k4 = flat & 15;
            const __hip_bfloat16* src = H1 + (size_t)(row0 + r) * 384 + kt + k4 * 4;
            *reinterpret_cast<uint2*>(&At[r * 68 + k4 * 4]) =
                *reinterpret_cast<const uint2*>(src);
        }
        for (int q = tid; q < 640; q += 256) {
            int j = q >> 6, k = q & 63;
            Wt[q] = Weff[j * 384 + kt + k];
        }
        __syncthreads();
        for (int k = 0; k < 64; k++) {
            float a = __bfloat162float(At[tid * 68 + k]);
#pragma unroll
            for (int j = 0; j < 10; j++) acc[j] += a * Wt[j * 64 + k];
        }
    }
#pragma unroll
    for (int j = 0; j < 10; j++) em[(size_t)(row0 + tid) * 10 + j] = acc[j] + bf[j];
}

// ---------------- CRF ----------------
__global__ __launch_bounds__(64) void crf_kernel(const float* __restrict__ em,
                                                 const int* __restrict__ tags,
                                                 const float* __restrict__ start_t,
                                                 const float* __restrict__ end_t,
                                                 const float* __restrict__ trans,
                                                 float* __restrict__ nll) {
    int s = blockIdx.x;
    int l = threadIdx.x;
    __shared__ float tr[100];
    __shared__ float aA[16], aB[16];
    if (l < 100) tr[l] = trans[l];
    if (l < 36)  tr[l + 64] = trans[l + 64];
    __syncthreads();

    float part = 0.f;
    for (int b = l; b < 256; b += 64) {
        int tg = tags[s * 256 + b];
        part += em[(size_t)(s * 256 + b) * 10 + tg];
        if (b > 0) {
            int tp = tags[s * 256 + b - 1];
            part += tr[tp * 10 + tg];
        }
    }
    for (int off = 32; off > 0; off >>= 1) part += __shfl_down(part, off);

    if (l < 10) aA[l] = start_t[l] + em[(size_t)(s * 256) * 10 + l];
    __syncthreads();
    for (int b = 1; b < 256; b++) {
        const float* rb = (b & 1) ? aA : aB;
        float* wb = (b & 1) ? aB : aA;
        if (l < 10) {
            float m = -1e30f;
            for (int i = 0; i < 10; i++) m = fmaxf(m, rb[i] + tr[i * 10 + l]);
            float ssum = 0.f;
            for (int i = 0; i < 10; i++) ssum += __expf(rb[i] + tr[i * 10 + l] - m);
            wb[l] = em[(size_t)(s * 256 + b) * 10 + l] + m + __logf(ssum);
        }
        __syncthreads();
    }
    if (l == 0) {
        const float* af = aB;
        float m = -1e30f;
        for (int i = 0; i < 10; i++) m = fmaxf(m, af[i] + end_t[i]);
        float ssum = 0.f;
        for (int i = 0; i < 10; i++) ssum += __expf(af[i] + end_t[i] - m);
        float logZ = m + __logf(ssum);
        float score = part + start_t[tags[s * 256]] + end_t[tags[s * 256 + 255]];
        nll[s] = logZ - score;
    }
}

__global__ __launch_bounds__(256) void reduce_k(const float* __restrict__ nll,
                                                float* __restrict__ out) {
    __shared__ float sm[256];
    int t = threadIdx.x;
    sm[t] = nll[t];
    __syncthreads();
    for (int s = 128; s > 0; s >>= 1) {
        if (t < s) sm[t] += sm[t + s];
        __syncthreads();
    }
    if (t == 0) out[0] = sm[0];
}

// ---------------- host ----------------

extern "C" void kernel_launch(void* const* d_in, const int* in_sizes, int n_in,
                              void* d_out, int out_size, void* d_ws, size_t ws_size,
                              hipStream_t stream) {
    const float* x     = (const float*)d_in[0];
    const int*   tags  = (const int*)d_in[2];
    const float* Wih0  = (const float*)d_in[3];
    const float* Whh0  = (const float*)d_in[4];
    const float* bih0  = (const float*)d_in[5];
    const float* bhh0  = (const float*)d_in[6];
    const float* Wih1  = (const float*)d_in[7];
    const float* Whh1  = (const float*)d_in[8];
    const float* bih1  = (const float*)d_in[9];
    const float* bhh1  = (const float*)d_in[10];
    const float* W1    = (const float*)d_in[11];
    const float* b1    = (const float*)d_in[12];
    const float* W2    = (const float*)d_in[13];
    const float* b2    = (const float*)d_in[14];
    const float* W3    = (const float*)d_in[15];
    const float* b3    = (const float*)d_in[16];
    const float* start_t = (const float*)d_in[17];
    const float* end_t   = (const float*)d_in[18];
    const float* trans   = (const float*)d_in[19];

    char* ws = (char*)d_ws;
    size_t off = 0;
    auto alloc = [&](size_t bytes) { void* p = ws + off; off += (bytes + 255) & ~(size_t)255; return p; };

    __hip_bfloat16* Xb    = (__hip_bfloat16*)alloc((size_t)65536 * 128 * 2);
    __hip_bfloat16* Wcat0 = (__hip_bfloat16*)alloc((size_t)1536 * 512 * 2);
    __hip_bfloat16* Wcat1 = (__hip_bfloat16*)alloc((size_t)1536 * 768 * 2);
    __hip_bfloat16* H0b   = (__hip_bfloat16*)alloc((size_t)257 * 98304 * 2);
    __hip_bfloat16* H1b   = (__hip_bfloat16*)alloc((size_t)257 * 98304 * 2);
    float* EM   = (float*)alloc((size_t)65536 * 10 * 4);
    float* Wtmp = (float*)alloc((size_t)10 * 512 * 4);
    float* Weff = (float*)alloc((size_t)10 * 384 * 4);
    float* beff = (float*)alloc(256);
    float* nll  = (float*)alloc(256 * 4);
    unsigned* bar = (unsigned*)alloc(4096 * 4);

    // prep
    prep_x<<<4096, 256, 0, stream>>>(x, Xb);
    prep_wcat<<<dim3(2, 1536), 256, 0, stream>>>(Wih0, 100, 128, Whh0, Wcat0, 512);
    prep_wcat<<<dim3(3, 1536), 256, 0, stream>>>(Wih1, 384, 384, Whh1, Wcat1, 768);
    init_zero<<<384, 256, 0, stream>>>(H0b, H1b, bar);
    wtmp_k<<<20, 256, 0, stream>>>(W3, W2, Wtmp);
    weff_k<<<15, 256, 0, stream>>>(Wtmp, W1, Weff);
    beff_k<<<1, 256, 0, stream>>>(W3, b2, Wtmp, b1, b3, beff);

    // persistent LSTM: 192 x 512-thread blocks; L2-scope sync + per-wave publish
    lstm_persistent<<<192, 512, 0, stream>>>(Xb, Wcat0, Wcat1,
                                             bih0, bhh0, bih1, bhh1,
                                             H0b, H1b, bar);

    // emissions + CRF
    em_kernel<<<256, 256, 0, stream>>>(H1b + 98304, Weff, beff, EM);
    crf_kernel<<<256, 64, 0, stream>>>(EM, tags, start_t, end_t, trans, nll);
    reduce_k<<<1, 256, 0, stream>>>(nll, (float*)d_out);
}

// Round 7
// 1364.040 us; speedup vs baseline: 93.4004x; 93.4004x over previous
//
#include <hip/hip_runtime.h>
#include <hip/hip_bf16.h>

typedef __bf16 bf16x8 __attribute__((ext_vector_type(8)));
typedef __bf16 bf16x4 __attribute__((ext_vector_type(4)));
typedef float floatx4 __attribute__((ext_vector_type(4)));
typedef unsigned long long ull;

#define AGT __HIP_MEMORY_SCOPE_AGENT

// ---- communication primitives ----
// AGT (sc1/L3): proven cross-XCD visibility (r0/r5). SLOW path + rendezvous.
__device__ __forceinline__ ull cload(const ull* p) {
    return __hip_atomic_load(const_cast<ull*>(p), __ATOMIC_RELAXED, AGT);
}
__device__ __forceinline__ unsigned fload(const unsigned* p) {
    return __hip_atomic_load(const_cast<unsigned*>(p), __ATOMIC_RELAXED, AGT);
}
__device__ __forceinline__ void cstore32(unsigned* p, unsigned v) {
    __hip_atomic_store(p, v, __ATOMIC_RELAXED, AGT);
}
// L2-executed atomics via inline asm. Evidence ledger:
//   r4: sc0 LOADS can be served stale from L1 -> polls never see updates.
//   r6: __hip_atomic_fetch_add(p,0) is InstCombine'd to an atomic LOAD
//       (idempotent-RMW elimination) -> same stale-L1 failure.
// Inline asm emits a real global_atomic_add that must execute at the XCD L2.
__device__ __forceinline__ void l2add_nr(unsigned* p, unsigned v) {
    asm volatile("global_atomic_add %0, %1, off"
                 :: "v"(p), "v"(v) : "memory");
}
__device__ __forceinline__ unsigned l2add_ret0(unsigned* p) {
    unsigned old;
    asm volatile("global_atomic_add %0, %1, %2, off sc0\n\ts_waitcnt vmcnt(0)"
                 : "=v"(old) : "v"(p), "v"(0u) : "memory");
    return old;
}
__device__ __forceinline__ float fsig(float x) { return 1.f / (1.f + __expf(-x)); }
__device__ __forceinline__ float ftanh(float x) { return 1.f - 2.f / (__expf(2.f * x) + 1.f); }

// ---------------- prep kernels ----------------

__global__ __launch_bounds__(256) void prep_x(const float* __restrict__ x,
                                              __hip_bfloat16* __restrict__ Xb) {
    int t = blockIdx.x * 256 + threadIdx.x;
    int row = t >> 4, c8 = (t & 15) * 8;
    union { __hip_bfloat16 h[8]; uint4 u; } pk;
#pragma unroll
    for (int j = 0; j < 8; j++) {
        int col = c8 + j;
        float v = (col < 100) ? x[row * 100 + col] : 0.f;
        pk.h[j] = __float2bfloat16(v);
    }
    *reinterpret_cast<uint4*>(Xb + (size_t)row * 128 + c8) = pk.u;
}

__global__ __launch_bounds__(256) void prep_wcat(const float* __restrict__ Wih, int Kin, int K1,
                                                 const float* __restrict__ Whh,
                                                 __hip_bfloat16* __restrict__ Wcat, int ldW) {
    int k = blockIdx.x * 256 + threadIdx.x;
    int row = blockIdx.y;
    if (k >= ldW) return;
    float v;
    if (k < K1) v = (k < Kin) ? Wih[row * Kin + k] : 0.f;
    else        v = Whh[row * 384 + (k - K1)];
    Wcat[row * ldW + k] = __float2bfloat16(v);
}

__global__ __launch_bounds__(256) void init_zero(__hip_bfloat16* __restrict__ H0b,
                                                 __hip_bfloat16* __restrict__ H1b,
                                                 unsigned* __restrict__ bar) {
    int i = blockIdx.x * 256 + threadIdx.x;
    __hip_bfloat16 z = __float2bfloat16(0.f);
    H0b[i] = z; H1b[i] = z;
    if (i < 4096) bar[i] = 0u;
}

__global__ __launch_bounds__(256) void wtmp_k(const float* __restrict__ W3,
                                              const float* __restrict__ W2,
                                              float* __restrict__ Wtmp) {
    int idx = blockIdx.x * 256 + threadIdx.x;
    int j = idx / 512, i = idx % 512;
    float a[8] = {0,0,0,0,0,0,0,0};
    for (int q = 0; q < 1024; q += 8) {
#pragma unroll
        for (int u = 0; u < 8; u++)
            a[u] += W3[j * 1024 + q + u] * W2[(q + u) * 512 + i];
    }
    Wtmp[idx] = ((a[0]+a[1])+(a[2]+a[3])) + ((a[4]+a[5])+(a[6]+a[7]));
}

__global__ __launch_bounds__(256) void weff_k(const float* __restrict__ Wtmp,
                                              const float* __restrict__ W1,
                                              float* __restrict__ Weff) {
    int idx = blockIdx.x * 256 + threadIdx.x;
    if (idx >= 3840) return;
    int j = idx / 384, i = idx % 384;
    float a[8] = {0,0,0,0,0,0,0,0};
    for (int q = 0; q < 512; q += 8) {
#pragma unroll
        for (int u = 0; u < 8; u++)
            a[u] += Wtmp[j * 512 + q + u] * W1[(q + u) * 384 + i];
    }
    Weff[idx] = ((a[0]+a[1])+(a[2]+a[3])) + ((a[4]+a[5])+(a[6]+a[7]));
}

__global__ __launch_bounds__(256) void beff_k(const float* __restrict__ W3, const float* __restrict__ b2,
                       const float* __restrict__ Wtmp, const float* __restrict__ b1,
                       const float* __restrict__ b3, float* __restrict__ beff) {
    __shared__ float red[256];
    int tid = threadIdx.x;
    for (int j = 0; j < 10; j++) {
        float p = 0.f;
        for (int q = tid; q < 1024; q += 256) p += W3[j * 1024 + q] * b2[q];
        for (int q = tid; q < 512; q += 256)  p += Wtmp[j * 512 + q] * b1[q];
        red[tid] = p;
        __syncthreads();
        for (int s = 128; s > 0; s >>= 1) {
            if (tid < s) red[tid] += red[tid + s];
            __syncthreads();
        }
        if (tid == 0) beff[j] = red[0] + b3[j];
        __syncthreads();
    }
}

// ---------------- persistent pipelined LSTM (512-thread blocks) ----------------
// 192 blocks = 8 groups x 2 layers x 12 gate-blocks; all 24 blocks of a group
// share (bid mod 8) -> one XCD (r4/r5: rendezvous declares FAST on HW).
// r5 chassis (block publish, end barrier, 12t targets) measured 1238us == r0
// baseline. THIS ROUND changes ONE variable: FAST counters use inline-asm
// global_atomic_add (publish +1 no-return; poll +0 sc0 return-old) so the
// publish/poll pair meets at the XCD L2 atomic unit — immune to both stale-L1
// loads (r4) and idempotent-RMW elimination (r6). SLOW = proven AGT/L3.

__device__ __forceinline__ bf16x8 lds_frag(const short* As, int r, int k) {
    const short* p = As + r * 388 + k;
    bf16x4 lo = *reinterpret_cast<const bf16x4*>(p);
    bf16x4 hi = *reinterpret_cast<const bf16x4*>(p + 4);
    return __builtin_shufflevector(lo, hi, 0, 1, 2, 3, 4, 5, 6, 7);
}

// stage 32 rows x 384 bf16 (24576B) into LDS (row stride 388 shorts), 512 thr
template<int FAST>
__device__ __forceinline__ void stage512(short* As, const ull* src, int tid) {
    ull v[6];
#pragma unroll
    for (int i = 0; i < 6; i++)
        v[i] = FAST ? src[tid + 512 * i] : cload(src + tid + 512 * i);
#pragma unroll
    for (int i = 0; i < 6; i++) {
        int q = tid + 512 * i;          // 0..3071 (96 ull per row)
        int row = q / 96;
        int c8 = q - row * 96;
        *reinterpret_cast<ull*>(As + row * 388 + c8 * 4) = v[i];
    }
}
// stage two slices, all 12 loads outstanding before scatter
template<int FAST>
__device__ __forceinline__ void stage512x2(short* Asa, const ull* sa,
                                           short* Asb, const ull* sb, int tid) {
    ull va[6], vb[6];
#pragma unroll
    for (int i = 0; i < 6; i++)
        va[i] = FAST ? sa[tid + 512 * i] : cload(sa + tid + 512 * i);
#pragma unroll
    for (int i = 0; i < 6; i++)
        vb[i] = FAST ? sb[tid + 512 * i] : cload(sb + tid + 512 * i);
#pragma unroll
    for (int i = 0; i < 6; i++) {
        int q = tid + 512 * i;
        int row = q / 96;
        int c8 = q - row * 96;
        *reinterpret_cast<ull*>(Asa + row * 388 + c8 * 4) = va[i];
        *reinterpret_cast<ull*>(Asb + row * 388 + c8 * 4) = vb[i];
    }
}

template<int L, int FAST>
__device__ void run_chain(
    const __hip_bfloat16* __restrict__ Xb,
    const __hip_bfloat16* __restrict__ Wcat,
    const float* __restrict__ bih, const float* __restrict__ bhh,
    const __hip_bfloat16* __restrict__ Hin,   // L=1: producer's H0
    __hip_bfloat16* __restrict__ Hown,
    unsigned* ctr_own, unsigned* ctr_prod,
    short* As1, short* As2, float* gbuf,
    int g, int bsub, int tid)
{
    constexpr int NKI = (L ? 12 : 4);
    constexpr int NK  = NKI + 12;
    constexpr int LDW = (L ? 768 : 512);
    int lane = tid & 63, wv = tid >> 6;        // wv 0..7
    int g4 = wv & 3, nt = wv >> 2;             // gate, n-half
    int lane15 = lane & 15, koff = (lane >> 4) * 8;

    // ---- register-resident weight fragments: ONE nt per wave ----
    bf16x8 bw[NK];
    {
        const __hip_bfloat16* Wrow =
            Wcat + (size_t)(g4 * 384 + bsub * 32 + nt * 16 + lane15) * LDW;
#pragma unroll
        for (int kk = 0; kk < NK; kk++)
            bw[kk] = *reinterpret_cast<const bf16x8*>(Wrow + kk * 32 + koff);
    }

    // ---- cell-thread state: m = tid>>4 (0..31), dims d0..d0+1 ----
    int m = tid >> 4, d0 = (tid & 15) * 2;
    int dgl = bsub * 32 + d0;
    float bb[4][2];
#pragma unroll
    for (int j = 0; j < 4; j++)
#pragma unroll
        for (int jj = 0; jj < 2; jj++)
            bb[j][jj] = bih[j * 384 + dgl + jj] + bhh[j * 384 + dgl + jj];
    float cst[2] = {0.f, 0.f};

    const __hip_bfloat16* XbRow = (L == 0) ? (Xb + (size_t)(g * 32 + lane15) * 128 + koff) : nullptr;
    unsigned* hout = reinterpret_cast<unsigned*>(Hown + (size_t)(g * 32 + m) * 384 + dgl);
    const ull* hsrc_own = reinterpret_cast<const ull*>(Hown + (size_t)g * 12288);
    const ull* hsrc_in  = L ? reinterpret_cast<const ull*>(Hin + (size_t)g * 12288) : nullptr;

    int r0 = (lane >> 4) * 4, ccol = lane15;

    // guards: legit waits are <<100 iters. Worst-case broken sync completes the
    // bench (passed, ~0.3s, diagnosable) instead of hanging the container.
    constexpr unsigned GUARD = FAST ? (1u << 12) : (1u << 13);

#pragma unroll 1
    for (int t = 0; t < 256; t++) {
        // ---- L0: prefetch Xb fragments (h-independent) under the poll ----
        bf16x8 ax[2][4];
        if (L == 0) {
            const __hip_bfloat16* A1p = XbRow + (size_t)t * 32768;
#pragma unroll
            for (int mt = 0; mt < 2; mt++)
#pragma unroll
                for (int kk = 0; kk < 4; kk++)
                    ax[mt][kk] = *reinterpret_cast<const bf16x8*>(A1p + mt * 2048 + kk * 32);
        }

        // ---- wait: own ctr >= 12t; L1 also producer >= 12(t+1) ----
        if (tid < 64) {
            if (FAST) {
                // lanes 0 (own) / 1 (producer, L1 only) poll via L2 atomic RMW
                for (unsigned it = 0; ; ++it) {
                    unsigned f = 0xFFFFFFFFu, nv = 0u;
                    if (lane == 0)                { f = l2add_ret0(ctr_own);  nv = 12u * (unsigned)t; }
                    else if (L == 1 && lane == 1) { f = l2add_ret0(ctr_prod); nv = 12u * (unsigned)(t + 1); }
                    if (__ballot(f >= nv) == ~0ull) break;
                    if (it > GUARD) break;
                }
            } else {
                unsigned need = 12u * (unsigned)t;
                const unsigned* pp = ctr_own;
                if (L == 1 && lane == 1) { pp = ctr_prod; need += 12u; }
                for (unsigned it = 0; ; ++it) {
                    unsigned f = fload(pp);
                    if (__ballot(f >= need) == ~0ull) break;
                    if (it > GUARD) break;
                    __builtin_amdgcn_s_sleep(1);
                }
            }
        }
        __syncthreads();
        asm volatile("" ::: "memory");

        floatx4 acc[2];
        acc[0] = floatx4{0.f, 0.f, 0.f, 0.f};
        acc[1] = floatx4{0.f, 0.f, 0.f, 0.f};

        if (L == 0) {
            stage512<FAST>(As2, hsrc_own + (size_t)t * 12288, tid);
            // input-part MFMAs overlap the stage loads
#pragma unroll
            for (int kk = 0; kk < 4; kk++)
#pragma unroll
                for (int mt = 0; mt < 2; mt++)
                    acc[mt] = __builtin_amdgcn_mfma_f32_16x16x32_bf16(ax[mt][kk], bw[kk], acc[mt], 0, 0, 0);
            __syncthreads();
        } else {
            stage512x2<FAST>(As1, hsrc_in + (size_t)(t + 1) * 12288,
                             As2, hsrc_own + (size_t)t * 12288, tid);
            __syncthreads();
#pragma unroll
            for (int kk = 0; kk < 12; kk++)
#pragma unroll
                for (int mt = 0; mt < 2; mt++) {
                    bf16x8 a = lds_frag(As1, mt * 16 + lane15, kk * 32 + koff);
                    acc[mt] = __builtin_amdgcn_mfma_f32_16x16x32_bf16(a, bw[kk], acc[mt], 0, 0, 0);
                }
        }
#pragma unroll
        for (int kk = 0; kk < 12; kk++)
#pragma unroll
            for (int mt = 0; mt < 2; mt++) {
                bf16x8 a = lds_frag(As2, mt * 16 + lane15, kk * 32 + koff);
                acc[mt] = __builtin_amdgcn_mfma_f32_16x16x32_bf16(a, bw[NKI + kk], acc[mt], 0, 0, 0);
            }
        if (L == 1) __syncthreads();   // gbuf aliases As1 (read by L1 MFMAs)

        // ---- gates to LDS: C layout row=(lane>>4)*4+r, col=lane&15 ----
#pragma unroll
        for (int mt = 0; mt < 2; mt++)
#pragma unroll
            for (int r = 0; r < 4; r++)
                gbuf[g4 * 1056 + (mt * 16 + r0 + r) * 33 + nt * 16 + ccol] = acc[mt][r];
        __syncthreads();

        // ---- cell update (2 dims/thread) + h store ----
        union { unsigned u; __hip_bfloat16 h[2]; } pk;
#pragma unroll
        for (int jj = 0; jj < 2; jj++) {
            float gi = gbuf[0 * 1056 + m * 33 + d0 + jj] + bb[0][jj];
            float gf = gbuf[1 * 1056 + m * 33 + d0 + jj] + bb[1][jj];
            float gg = gbuf[2 * 1056 + m * 33 + d0 + jj] + bb[2][jj];
            float go = gbuf[3 * 1056 + m * 33 + d0 + jj] + bb[3][jj];
            float c = fsig(gf) * cst[jj] + fsig(gi) * ftanh(gg);
            cst[jj] = c;
            pk.h[jj] = __float2bfloat16(fsig(go) * ftanh(c));
        }
        if (FAST) *(hout + (size_t)(t + 1) * 49152) = pk.u;   // L2 write-through
        else      cstore32(hout + (size_t)(t + 1) * 49152, pk.u);

        __syncthreads();   // vmcnt(0) drained before barrier: h acked at L2/L3
        if (tid == 0) {
            if (FAST) l2add_nr(ctr_own, 1u);                                  // L2 atomic
            else      __hip_atomic_fetch_add(ctr_own, 1u, __ATOMIC_RELAXED, AGT); // L3
        }
    }
}

__global__ __launch_bounds__(512, 2) void lstm_persistent(
    const __hip_bfloat16* __restrict__ Xb,
    const __hip_bfloat16* __restrict__ Wcat0,
    const __hip_bfloat16* __restrict__ Wcat1,
    const float* __restrict__ bih0, const float* __restrict__ bhh0,
    const float* __restrict__ bih1, const float* __restrict__ bhh1,
    __hip_bfloat16* __restrict__ H0, __hip_bfloat16* __restrict__ H1,
    unsigned* __restrict__ bar)
{
    __shared__ __align__(16) char smem[49664];
    short* As1 = (short*)smem;              // L1 staged h0; aliases gbuf
    short* As2 = (short*)(smem + 24832);    // staged own h
    float* gbuf = (float*)smem;             // phase-disjoint with As1
    __shared__ int fast_s;

    int tid = threadIdx.x;
    int bid = blockIdx.x;
    // XCD-affine mapping: all 24 blocks of group g share (bid mod 8) == g.
    int g = bid & 7;
    int l = (bid >> 3) & 1;
    int bsub = bid >> 4;

    // ---- one-time rendezvous: publish XCC id, decide fast/slow per group ----
    // bar[0]=rendezvous ctr, bar[8..199]=xcc table (+1), bar[256..]=chain ctrs
    if (tid < 64) {
        unsigned xcc;
        asm volatile("s_getreg_b32 %0, hwreg(20, 0, 4)" : "=s"(xcc));  // HW_REG_XCC_ID
        if (tid == 0) {
            __hip_atomic_store(&bar[8 + bid], xcc + 1u, __ATOMIC_RELEASE, AGT);
            __hip_atomic_fetch_add(&bar[0], 1u, __ATOMIC_RELEASE, AGT);
        }
        unsigned r;
        unsigned it2 = 0;
        do {
            r = __hip_atomic_load(&bar[0], __ATOMIC_ACQUIRE, AGT);
            if (r < 192u) __builtin_amdgcn_s_sleep(8);
            if (++it2 > (1u << 22)) break;   // hang guard (~1s); forces fallback
        } while (r < 192u);
        int ok = (r >= 192u) ? 1 : 0;        // rendezvous timeout -> slow path
        if (ok && tid < 24) {   // my group's 24 members all on my XCC?
            int ob = g + (tid & 1) * 8 + (tid >> 1) * 16;
            ok = (fload(&bar[8 + ob]) == xcc + 1u);
        }
        int fast = (__ballot(ok) == ~0ull) ? 1 : 0;
        if (tid == 0) {
            // hwreg sanity: 8 group representatives must be pairwise distinct
            unsigned rep[8];
            for (int j = 0; j < 8; j++) rep[j] = fload(&bar[8 + j]);
            for (int a2 = 0; a2 < 8; a2++)
                for (int b2 = a2 + 1; b2 < 8; b2++)
                    if (rep[a2] == rep[b2]) fast = 0;
            fast_s = fast;
        }
    }
    __syncthreads();
    int fast = fast_s;

    // chain ctr lines: one 64B line per chain -> pollers (<=24 atomics/round)
    // and 12 publishes/step serialize briefly at the L2 atomic unit; fine.
    unsigned* ctrs = bar + 256;
    unsigned* ctr_own = ctrs + (g * 2 + l) * 16;
    unsigned* ctr_prod = ctrs + (g * 2) * 16;  // L0 chain of this group

    if (l == 0) {
        if (fast) run_chain<0, 1>(Xb, Wcat0, bih0, bhh0, nullptr, H0,
                                  ctr_own, nullptr, As1, As2, gbuf, g, bsub, tid);
        else      run_chain<0, 0>(Xb, Wcat0, bih0, bhh0, nullptr, H0,
                                  ctr_own, nullptr, As1, As2, gbuf, g, bsub, tid);
    } else {
        if (fast) run_chain<1, 1>(nullptr, Wcat1, bih1, bhh1, H0, H1,
                                  ctr_own, ctr_prod, As1, As2, gbuf, g, bsub, tid);
        else      run_chain<1, 0>(nullptr, Wcat1, bih1, bhh1, H0, H1,
                                  ctr_own, ctr_prod, As1, As2, gbuf, g, bsub, tid);
    }
}

// ---------------- emissions ----------------
__global__ __launch_bounds__(256) void em_kernel(const __hip_bfloat16* __restrict__ H1,
                                                 const float* __restrict__ Weff,
                                                 const float* __restrict__ beff,
                                                 float* __restrict__ em) {
    __shared__ __hip_bfloat16 At[256 * 68];
    __shared__ float Wt[640];
    __shared__ float bf[10];
    int tid = threadIdx.x;
    int row0 = blockIdx.x * 256;
    if (tid < 10) bf[tid] = beff[tid];
    float acc[10];
#pragma unroll
    for (int j = 0; j < 10; j++) acc[j] = 0.f;

    for (int kt = 0; kt < 384; kt += 64) {
        __syncthreads();
#pragma unroll
        for (int q = 0; q < 16; q++) {
            int flat = q * 256 + tid;
            int r = flat >> 4;
            int k4 = flat & 15;
            const __hip_bfloat16* src = H1 + (size_t)(row0 + r) * 384 + kt + k4 * 4;
            *reinterpret_cast<uint2*>(&At[r * 68 + k4 * 4]) =
                *reinterpret_cast<const uint2*>(src);
        }
        for (int q = tid; q < 640; q += 256) {
            int j = q >> 6, k = q & 63;
            Wt[q] = Weff[j * 384 + kt + k];
        }
        __syncthreads();
        for (int k = 0; k < 64; k++) {
            float a = __bfloat162float(At[tid * 68 + k]);
#pragma unroll
            for (int j = 0; j < 10; j++) acc[j] += a * Wt[j * 64 + k];
        }
    }
#pragma unroll
    for (int j = 0; j < 10; j++) em[(size_t)(row0 + tid) * 10 + j] = acc[j] + bf[j];
}

// ---------------- CRF ----------------
__global__ __launch_bounds__(64) void crf_kernel(const float* __restrict__ em,
                                                 const int* __restrict__ tags,
                                                 const float* __restrict__ start_t,
                                                 const float* __restrict__ end_t,
                                                 const float* __restrict__ trans,
                                                 float* __restrict__ nll) {
    int s = blockIdx.x;
    int l = threadIdx.x;
    __shared__ float tr[100];
    __shared__ float aA[16], aB[16];
    if (l < 100) tr[l] = trans[l];
    if (l < 36)  tr[l + 64] = trans[l + 64];
    __syncthreads();

    float part = 0.f;
    for (int b = l; b < 256; b += 64) {
        int tg = tags[s * 256 + b];
        part += em[(size_t)(s * 256 + b) * 10 + tg];
        if (b > 0) {
            int tp = tags[s * 256 + b - 1];
            part += tr[tp * 10 + tg];
        }
    }
    for (int off = 32; off > 0; off >>= 1) part += __shfl_down(part, off);

    if (l < 10) aA[l] = start_t[l] + em[(size_t)(s * 256) * 10 + l];
    __syncthreads();
    for (int b = 1; b < 256; b++) {
        const float* rb = (b & 1) ? aA : aB;
        float* wb = (b & 1) ? aB : aA;
        if (l < 10) {
            float m = -1e30f;
            for (int i = 0; i < 10; i++) m = fmaxf(m, rb[i] + tr[i * 10 + l]);
            float ssum = 0.f;
            for (int i = 0; i < 10; i++) ssum += __expf(rb[i] + tr[i * 10 + l] - m);
            wb[l] = em[(size_t)(s * 256 + b) * 10 + l] + m + __logf(ssum);
        }
        __syncthreads();
    }
    if (l == 0) {
        const float* af = aB;
        float m = -1e30f;
        for (int i = 0; i < 10; i++) m = fmaxf(m, af[i] + end_t[i]);
        float ssum = 0.f;
        for (int i = 0; i < 10; i++) ssum += __expf(af[i] + end_t[i] - m);
        float logZ = m + __logf(ssum);
        float score = part + start_t[tags[s * 256]] + end_t[tags[s * 256 + 255]];
        nll[s] = logZ - score;
    }
}

__global__ __launch_bounds__(256) void reduce_k(const float* __restrict__ nll,
                                                float* __restrict__ out) {
    __shared__ float sm[256];
    int t = threadIdx.x;
    sm[t] = nll[t];
    __syncthreads();
    for (int s = 128; s > 0; s >>= 1) {
        if (t < s) sm[t] += sm[t + s];
        __syncthreads();
    }
    if (t == 0) out[0] = sm[0];
}

// ---------------- host ----------------

extern "C" void kernel_launch(void* const* d_in, const int* in_sizes, int n_in,
                              void* d_out, int out_size, void* d_ws, size_t ws_size,
                              hipStream_t stream) {
    const float* x     = (const float*)d_in[0];
    const int*   tags  = (const int*)d_in[2];
    const float* Wih0  = (const float*)d_in[3];
    const float* Whh0  = (const float*)d_in[4];
    const float* bih0  = (const float*)d_in[5];
    const float* bhh0  = (const float*)d_in[6];
    const float* Wih1  = (const float*)d_in[7];
    const float* Whh1  = (const float*)d_in[8];
    const float* bih1  = (const float*)d_in[9];
    const float* bhh1  = (const float*)d_in[10];
    const float* W1    = (const float*)d_in[11];
    const float* b1    = (const float*)d_in[12];
    const float* W2    = (const float*)d_in[13];
    const float* b2    = (const float*)d_in[14];
    const float* W3    = (const float*)d_in[15];
    const float* b3    = (const float*)d_in[16];
    const float* start_t = (const float*)d_in[17];
    const float* end_t   = (const float*)d_in[18];
    const float* trans   = (const float*)d_in[19];

    char* ws = (char*)d_ws;
    size_t off = 0;
    auto alloc = [&](size_t bytes) { void* p = ws + off; off += (bytes + 255) & ~(size_t)255; return p; };

    __hip_bfloat16* Xb    = (__hip_bfloat16*)alloc((size_t)65536 * 128 * 2);
    __hip_bfloat16* Wcat0 = (__hip_bfloat16*)alloc((size_t)1536 * 512 * 2);
    __hip_bfloat16* Wcat1 = (__hip_bfloat16*)alloc((size_t)1536 * 768 * 2);
    __hip_bfloat16* H0b   = (__hip_bfloat16*)alloc((size_t)257 * 98304 * 2);
    __hip_bfloat16* H1b   = (__hip_bfloat16*)alloc((size_t)257 * 98304 * 2);
    float* EM   = (float*)alloc((size_t)65536 * 10 * 4);
    float* Wtmp = (float*)alloc((size_t)10 * 512 * 4);
    float* Weff = (float*)alloc((size_t)10 * 384 * 4);
    float* beff = (float*)alloc(256);
    float* nll  = (float*)alloc(256 * 4);
    unsigned* bar = (unsigned*)alloc(4096 * 4);

    // prep
    prep_x<<<4096, 256, 0, stream>>>(x, Xb);
    prep_wcat<<<dim3(2, 1536), 256, 0, stream>>>(Wih0, 100, 128, Whh0, Wcat0, 512);
    prep_wcat<<<dim3(3, 1536), 256, 0, stream>>>(Wih1, 384, 384, Whh1, Wcat1, 768);
    init_zero<<<384, 256, 0, stream>>>(H0b, H1b, bar);
    wtmp_k<<<20, 256, 0, stream>>>(W3, W2, Wtmp);
    weff_k<<<15, 256, 0, stream>>>(Wtmp, W1, Weff);
    beff_k<<<1, 256, 0, stream>>>(W3, b2, Wtmp, b1, b3, beff);

    // persistent LSTM: 192 x 512-thread blocks; L2-atomic sync (inline asm)
    lstm_persistent<<<192, 512, 0, stream>>>(Xb, Wcat0, Wcat1,
                                             bih0, bhh0, bih1, bhh1,
                                             H0b, H1b, bar);

    // emissions + CRF
    em_kernel<<<256, 256, 0, stream>>>(H1b + 98304, Weff, beff, EM);
    crf_kernel<<<256, 64, 0, stream>>>(EM, tags, start_t, end_t, trans, nll);
    reduce_k<<<1, 256, 0, stream>>>(nll, (float*)d_out);
}